// Round 1
// baseline (1974.678 us; speedup 1.0000x reference)
//
#include <hip/hip_runtime.h>
#include <stdint.h>
#include <stddef.h>

#define M_DIM 8192
#define N_DIM 16384
#define K_DIM 4096

typedef unsigned short u16;
typedef __attribute__((ext_vector_type(8))) short short8;
typedef __attribute__((ext_vector_type(4))) float f32x4;

// fp32 -> bf16, round-to-nearest-even (branchless; inputs are finite normals)
__device__ __forceinline__ u16 f2bf(float f) {
    unsigned int u = __builtin_bit_cast(unsigned int, f);
    return (u16)((u + 0x7FFFu + ((u >> 16) & 1u)) >> 16);
}

// async global->LDS DMA, 16B per lane. LDS dest semantics: wave-uniform base +
// lane*16 (m104/m108) — our staging layout is contiguous in lane order.
__device__ __forceinline__ void gl2lds16(const void* g, void* l) {
    __builtin_amdgcn_global_load_lds(
        (const __attribute__((address_space(1))) unsigned int*)g,
        (__attribute__((address_space(3))) unsigned int*)l,
        16, 0, 0);
}

// ---------------- pass 1a: x fp32 -> bf16 ----------------
__global__ __launch_bounds__(256) void convert_x_kernel(
    const float* __restrict__ x, u16* __restrict__ xb) {
    int i = blockIdx.x * 256 + threadIdx.x;   // 8 elements per thread
    const float4* p = (const float4*)x + (size_t)i * 2;
    float4 a = p[0], b = p[1];
    union { u16 u[8]; short8 v; } o;
    o.u[0] = f2bf(a.x); o.u[1] = f2bf(a.y); o.u[2] = f2bf(a.z); o.u[3] = f2bf(a.w);
    o.u[4] = f2bf(b.x); o.u[5] = f2bf(b.y); o.u[6] = f2bf(b.z); o.u[7] = f2bf(b.w);
    *((short8*)xb + i) = o.v;
}

// ---------------- pass 1b: w_bf16 = bf16(qw * group_scale) ----------------
__global__ __launch_bounds__(256) void dequant_w_kernel(
    const float* __restrict__ qw, const float* __restrict__ sc, u16* __restrict__ wb) {
    int i = blockIdx.x * 256 + threadIdx.x;   // 8 k-contiguous elements per thread
    int row = i >> 9;                          // 4096/8 = 512 chunks per row
    int kc = i & 511;                          // chunk index; k = kc*8
    float s = sc[row * 32 + (kc >> 4)];        // group = (kc*8)>>7 = kc>>4
    const float4* p = (const float4*)qw + (size_t)i * 2;
    float4 a = p[0], b = p[1];
    union { u16 u[8]; short8 v; } o;
    o.u[0] = f2bf(a.x * s); o.u[1] = f2bf(a.y * s); o.u[2] = f2bf(a.z * s); o.u[3] = f2bf(a.w * s);
    o.u[4] = f2bf(b.x * s); o.u[5] = f2bf(b.y * s); o.u[6] = f2bf(b.z * s); o.u[7] = f2bf(b.w * s);
    *((short8*)wb + i) = o.v;
}

// ---------------- pass 2: C = A * B^T + bias (m97 structure) ----------------
// A: [M][K] bf16, B: [N][K] bf16, C: [M][N] fp32.
// 128x128 tile, BK=32; 4 waves in 2x2, each wave 64x64 via 4x4 MFMA 16x16x32.
__global__ __launch_bounds__(256) void gemm_bt_kernel(
    const u16* __restrict__ A, const u16* __restrict__ B,
    const float* __restrict__ bias, float* __restrict__ C) {
    __shared__ u16 sA[128 * 32];   // 8 KB, row-major [row][k], no padding (DMA constraint)
    __shared__ u16 sB[128 * 32];   // 8 KB

    const int tid   = threadIdx.x;
    const int lane  = tid & 63;
    const int wave  = tid >> 6;
    const int wm    = wave >> 1;     // 2x2 wave grid
    const int wn    = wave & 1;
    const int row16 = lane & 15;
    const int quad  = lane >> 4;
    const int bx = blockIdx.x;       // N tiles
    const int by = blockIdx.y;       // M tiles

    // staging addresses: thread t loads 16B = 8 bf16 at tile row t>>2, k-chunk (t&3)*8
    const u16* gA0 = A + (size_t)(by * 128 + (tid >> 2)) * K_DIM + (tid & 3) * 8;
    const u16* gA1 = gA0 + (size_t)64 * K_DIM;
    const u16* gB0 = B + (size_t)(bx * 128 + (tid >> 2)) * K_DIM + (tid & 3) * 8;
    const u16* gB1 = gB0 + (size_t)64 * K_DIM;
    u16* lA0 = &sA[tid * 8];
    u16* lA1 = &sA[2048 + tid * 8];
    u16* lB0 = &sB[tid * 8];
    u16* lB1 = &sB[2048 + tid * 8];

    f32x4 zero = {0.f, 0.f, 0.f, 0.f};
    f32x4 acc[4][4];
#pragma unroll
    for (int i = 0; i < 4; ++i)
#pragma unroll
        for (int j = 0; j < 4; ++j) acc[i][j] = zero;

    // fragment LDS offsets: A lane holds A[m=lane&15][k=quad*8+j]; B symmetric
    const int aoff = (wm * 64 + row16) * 32 + quad * 8;
    const int boff = (wn * 64 + row16) * 32 + quad * 8;

    for (int k0 = 0; k0 < K_DIM; k0 += 32) {
        __syncthreads();                 // all waves done reading prev tile
        gl2lds16(gA0 + k0, lA0);
        gl2lds16(gA1 + k0, lA1);
        gl2lds16(gB0 + k0, lB0);
        gl2lds16(gB1 + k0, lB1);
        __syncthreads();                 // compiler drains vmcnt(0) before barrier

        short8 aF[4], bF[4];
#pragma unroll
        for (int mi = 0; mi < 4; ++mi) aF[mi] = *(const short8*)&sA[aoff + mi * 16 * 32];
#pragma unroll
        for (int ni = 0; ni < 4; ++ni) bF[ni] = *(const short8*)&sB[boff + ni * 16 * 32];
#pragma unroll
        for (int mi = 0; mi < 4; ++mi)
#pragma unroll
            for (int ni = 0; ni < 4; ++ni)
                acc[mi][ni] = __builtin_amdgcn_mfma_f32_16x16x32_bf16(
                    aF[mi], bF[ni], acc[mi][ni], 0, 0, 0);
    }

    // epilogue: C/D layout col=lane&15, row=quad*4+reg (m89/m91 verified)
    const int rb = by * 128 + wm * 64 + quad * 4;
    const int cb = bx * 128 + wn * 64 + row16;
#pragma unroll
    for (int ni = 0; ni < 4; ++ni) {
        const int col = cb + ni * 16;
        const float bv = bias[col];
#pragma unroll
        for (int mi = 0; mi < 4; ++mi) {
            float* cp = C + (size_t)(rb + mi * 16) * N_DIM + col;
#pragma unroll
            for (int r = 0; r < 4; ++r) cp[(size_t)r * N_DIM] = acc[mi][ni][r] + bv;
        }
    }
}

// ---------------- fallback: fused dequant GEMM, fp32 staging (no workspace) ----------------
__global__ __launch_bounds__(256) void gemm_fused_kernel(
    const float* __restrict__ X, const float* __restrict__ QW,
    const float* __restrict__ S, const float* __restrict__ bias,
    float* __restrict__ C) {
    __shared__ u16 sA[128 * 32];
    __shared__ u16 sB[128 * 32];

    const int tid   = threadIdx.x;
    const int lane  = tid & 63;
    const int wave  = tid >> 6;
    const int wm    = wave >> 1;
    const int wn    = wave & 1;
    const int row16 = lane & 15;
    const int quad  = lane >> 4;
    const int bx = blockIdx.x;
    const int by = blockIdx.y;

    const int arow  = tid >> 1;            // staging row 0..127
    const int ahalf = (tid & 1) * 16;      // 16-col half of BK=32
    const float* gA = X  + (size_t)(by * 128 + arow) * K_DIM + ahalf;
    const float* gB = QW + (size_t)(bx * 128 + arow) * K_DIM + ahalf;
    const float* gS = S  + (size_t)(bx * 128 + arow) * 32;

    f32x4 zero = {0.f, 0.f, 0.f, 0.f};
    f32x4 acc[4][4];
#pragma unroll
    for (int i = 0; i < 4; ++i)
#pragma unroll
        for (int j = 0; j < 4; ++j) acc[i][j] = zero;

    const int aoff = (wm * 64 + row16) * 32 + quad * 8;
    const int boff = (wn * 64 + row16) * 32 + quad * 8;

    for (int k0 = 0; k0 < K_DIM; k0 += 32) {
        float4 va[4], vb[4];
#pragma unroll
        for (int j = 0; j < 4; ++j) {
            va[j] = *(const float4*)(gA + k0 + j * 4);
            vb[j] = *(const float4*)(gB + k0 + j * 4);
        }
        const float s = gS[k0 >> 7];   // group uniform across BK=32 (32 | 128)
        __syncthreads();               // prev iter's ds_reads done
        union { u16 u[16]; short8 v[2]; } ua, ub;
#pragma unroll
        for (int j = 0; j < 4; ++j) {
            ua.u[j*4+0] = f2bf(va[j].x);     ua.u[j*4+1] = f2bf(va[j].y);
            ua.u[j*4+2] = f2bf(va[j].z);     ua.u[j*4+3] = f2bf(va[j].w);
            ub.u[j*4+0] = f2bf(vb[j].x * s); ub.u[j*4+1] = f2bf(vb[j].y * s);
            ub.u[j*4+2] = f2bf(vb[j].z * s); ub.u[j*4+3] = f2bf(vb[j].w * s);
        }
        *(short8*)&sA[arow * 32 + ahalf]     = ua.v[0];
        *(short8*)&sA[arow * 32 + ahalf + 8] = ua.v[1];
        *(short8*)&sB[arow * 32 + ahalf]     = ub.v[0];
        *(short8*)&sB[arow * 32 + ahalf + 8] = ub.v[1];
        __syncthreads();

        short8 aF[4], bF[4];
#pragma unroll
        for (int mi = 0; mi < 4; ++mi) aF[mi] = *(const short8*)&sA[aoff + mi * 16 * 32];
#pragma unroll
        for (int ni = 0; ni < 4; ++ni) bF[ni] = *(const short8*)&sB[boff + ni * 16 * 32];
#pragma unroll
        for (int mi = 0; mi < 4; ++mi)
#pragma unroll
            for (int ni = 0; ni < 4; ++ni)
                acc[mi][ni] = __builtin_amdgcn_mfma_f32_16x16x32_bf16(
                    aF[mi], bF[ni], acc[mi][ni], 0, 0, 0);
    }

    const int rb = by * 128 + wm * 64 + quad * 4;
    const int cb = bx * 128 + wn * 64 + row16;
#pragma unroll
    for (int ni = 0; ni < 4; ++ni) {
        const int col = cb + ni * 16;
        const float bv = bias[col];
#pragma unroll
        for (int mi = 0; mi < 4; ++mi) {
            float* cp = C + (size_t)(rb + mi * 16) * N_DIM + col;
#pragma unroll
            for (int r = 0; r < 4; ++r) cp[(size_t)r * N_DIM] = acc[mi][ni][r] + bv;
        }
    }
}

extern "C" void kernel_launch(void* const* d_in, const int* in_sizes, int n_in,
                              void* d_out, int out_size, void* d_ws, size_t ws_size,
                              hipStream_t stream) {
    const float* x    = (const float*)d_in[0];  // [4,2048,4096]
    const float* qw   = (const float*)d_in[1];  // [16384,4096]
    const float* sc   = (const float*)d_in[2];  // [16384,32]
    const float* bias = (const float*)d_in[3];  // [16384]
    float* out = (float*)d_out;                 // [8192,16384]

    const size_t needA = (size_t)M_DIM * K_DIM * sizeof(u16);  // 64 MB
    const size_t needB = (size_t)N_DIM * K_DIM * sizeof(u16);  // 128 MB
    dim3 grid(N_DIM / 128, M_DIM / 128);

    if (ws_size >= needA + needB) {
        u16* xb = (u16*)d_ws;
        u16* wb = xb + (size_t)M_DIM * K_DIM;
        convert_x_kernel<<<(M_DIM * (size_t)K_DIM) / (8 * 256), 256, 0, stream>>>(x, xb);
        dequant_w_kernel<<<(N_DIM * (size_t)K_DIM) / (8 * 256), 256, 0, stream>>>(qw, sc, wb);
        gemm_bt_kernel<<<grid, 256, 0, stream>>>(xb, wb, bias, out);
    } else {
        gemm_fused_kernel<<<grid, 256, 0, stream>>>(x, qw, sc, bias, out);
    }
}